// Round 13
// baseline (14.072 us; speedup 1.0000x reference)
//
#include <hip/hip_runtime.h>

// Dist_Conv2D: out[b,f,h,w] = max_{c,i,j} |W[f, c*9+i*3+j] - x_pad[b,c,h+i,w+j]| + bias[f]
// x: (4,16,64,64) f32, W: (64,144) f32, bias: (64,) f32, out: (4,64,64,64) f32
// replicate pad 1 each side of H,W.
//
// R13: R5 base (best, 13.42us) + ONE change: max chain written as
// fmaxf(fmaxf(a,|d0|),|d1|) pairs -> clang fuses each to v_max3_f32 with abs
// source modifiers. 9 max-slots -> 5 per (c,fi); subs stay scalar (packing
// fp32 pairs is mov-bound per R10/R11; asm is scheduler-opaque per R8).
// Keep: 3-load + DPP stencil (R5), SGPR weights (R4), FCHUNK=4/1024 blocks,
// unroll 4 (full unroll = icache cost, R7), no min-waves bound (R2).

#define BB 4
#define CC 16
#define HH 64
#define WW 64
#define FF 64
#define FCHUNK 4

#define DPP_LEFT(v)  __int_as_float(__builtin_amdgcn_update_dpp(            \
        __float_as_int(v), __float_as_int(v), 0x138, 0xf, 0xf, false))
#define DPP_RIGHT(v) __int_as_float(__builtin_amdgcn_update_dpp(            \
        __float_as_int(v), __float_as_int(v), 0x130, 0xf, 0xf, false))

__global__ __launch_bounds__(256) void dist_conv2d_kernel(
    const float* __restrict__ x,
    const float* __restrict__ wgt,
    const float* __restrict__ bias,
    float* __restrict__ out) {
    // block = 256 threads = (h_lo(2) | w(6)); blockIdx bits: fc(4)|b(2)|h_hi(4)
    int w  = threadIdx.x & 63;             // lane id
    int h  = ((blockIdx.x & 15) << 2) | (threadIdx.x >> 6);
    int b  = (blockIdx.x >> 4) & 3;        // SGPR
    int fc = blockIdx.x >> 6;              // SGPR, 0..15
    int f0 = fc * FCHUNK;                  // SGPR

    // replicate-pad clamped row indices (columns via DPP boundary rule)
    int r0 = h - 1; if (r0 < 0) r0 = 0;
    int r2 = h + 1; if (r2 > HH - 1) r2 = HH - 1;
    int row0 = r0 * WW + w, row1 = h * WW + w, row2 = r2 * WW + w;

    float dist[FCHUNK];
#pragma unroll
    for (int i = 0; i < FCHUNK; ++i) dist[i] = 0.0f;

    const float* xb    = x + b * (CC * HH * WW);
    const float* wbase = wgt + f0 * (CC * 9);        // SGPR base -> s_load

#pragma unroll 4
    for (int c = 0; c < CC; ++c) {
        const float* xc = xb + c * (HH * WW);
        float v0 = xc[row0], v1 = xc[row1], v2 = xc[row2];   // 3 loads/channel
        float p[9];
        p[0] = DPP_LEFT(v0);  p[1] = v0;  p[2] = DPP_RIGHT(v0);
        p[3] = DPP_LEFT(v1);  p[4] = v1;  p[5] = DPP_RIGHT(v1);
        p[6] = DPP_LEFT(v2);  p[7] = v2;  p[8] = DPP_RIGHT(v2);
#pragma unroll
        for (int fi = 0; fi < FCHUNK; ++fi) {
            const float* wrow = wbase + fi * (CC * 9) + c * 9;   // uniform -> s_load
            float d0 = p[0] - wrow[0], d1 = p[1] - wrow[1], d2 = p[2] - wrow[2];
            float d3 = p[3] - wrow[3], d4 = p[4] - wrow[4], d5 = p[5] - wrow[5];
            float d6 = p[6] - wrow[6], d7 = p[7] - wrow[7], d8 = p[8] - wrow[8];
            float a = dist[fi];
            a = fmaxf(fmaxf(a, fabsf(d0)), fabsf(d1));   // -> v_max3_f32 |..| |..|
            a = fmaxf(fmaxf(a, fabsf(d2)), fabsf(d3));
            a = fmaxf(fmaxf(a, fabsf(d4)), fabsf(d5));
            a = fmaxf(fmaxf(a, fabsf(d6)), fabsf(d7));
            a = fmaxf(a, fabsf(d8));
            dist[fi] = a;
        }
    }

    float* ob = out + ((b * FF + f0) * HH + h) * WW + w;
#pragma unroll
    for (int fi = 0; fi < FCHUNK; ++fi) {
        ob[fi * (HH * WW)] = dist[fi] + bias[f0 + fi];   // bias: s_load
    }
}

extern "C" void kernel_launch(void* const* d_in, const int* in_sizes, int n_in,
                              void* d_out, int out_size, void* d_ws, size_t ws_size,
                              hipStream_t stream) {
    const float* x    = (const float*)d_in[0];
    const float* wgt  = (const float*)d_in[1];
    const float* bias = (const float*)d_in[2];
    float* out = (float*)d_out;

    const int total = (FF / FCHUNK) * BB * HH * WW;  // 262144 threads, 1024 blocks
    dist_conv2d_kernel<<<total / 256, 256, 0, stream>>>(x, wgt, bias, out);
}